// Round 10
// baseline (964.847 us; speedup 1.0000x reference)
//
#include <hip/hip_runtime.h>
#include <math.h>

#define NEG_SLOPE 0.2f

typedef __attribute__((ext_vector_type(8))) short short8;
typedef __attribute__((ext_vector_type(4))) float floatx4;

// ---------------- fp32 <-> bf16 split helpers (RNE) ----------------
__device__ __forceinline__ unsigned short f2bf(float f) {
    unsigned u = __float_as_uint(f);
    u += 0x7fffu + ((u >> 16) & 1u);
    return (unsigned short)(u >> 16);
}
__device__ __forceinline__ float bf2f(unsigned short h) {
    return __uint_as_float((unsigned)h << 16);
}
__device__ __forceinline__ float lrelu(float v) {
    return v > 0.f ? v : NEG_SLOPE * v;
}

// ---------------- fused weight pre-pass: 8 jobs in one launch ----------------
struct SJob { const float* W; unsigned short* Th; unsigned short* Tl; int K, N, Kp, base; };
struct SJobs { SJob j[8]; };

__global__ __launch_bounds__(256) void split_transpose_multi(SJobs js) {
    int t = blockIdx.x;
    int ji = 0;
#pragma unroll
    for (int q = 1; q < 8; ++q) if (t >= js.j[q].base) ji = q;
    const SJob jb = js.j[ji];
    int local = t - jb.base;
    int ntiles = jb.N / 32;
    int tn = local % ntiles, tk = local / ntiles;
    int k0 = tk * 32, n0 = tn * 32;
    __shared__ float tbuf[32][33];
    int c = threadIdx.x & 31, r = threadIdx.x >> 5;
    for (int rr = r; rr < 32; rr += 8) {
        int k = k0 + rr, n = n0 + c;
        tbuf[rr][c] = (k < jb.K && n < jb.N) ? jb.W[(long)k * jb.N + n] : 0.f;
    }
    __syncthreads();
    for (int rr = r; rr < 32; rr += 8) {
        int n = n0 + rr, k = k0 + c;
        if (n < jb.N && k < jb.Kp) {
            float v = tbuf[c][rr];
            unsigned short h = f2bf(v);
            jb.Th[(long)n * jb.Kp + k] = h;
            jb.Tl[(long)n * jb.Kp + k] = f2bf(v - bf2f(h));
        }
    }
}

// ---- 4 fused matvecs: wa[k] = sum_n W[k][n]*a[n] (k in [0,256) each) ----
__global__ __launch_bounds__(256) void matvec4(
    const float* __restrict__ gdW, const float* __restrict__ gdas, const float* __restrict__ gdad,
    float* __restrict__ wds, float* __restrict__ wdd,
    const float* __restrict__ g1W, const float* __restrict__ g1as, const float* __restrict__ g1ad,
    float* __restrict__ w1s, float* __restrict__ w1d)
{
    int b = blockIdx.x;
    int sel = b >> 8, k = b & 255, t = threadIdx.x;
    const float *W, *a; float* o; int N;
    if (sel == 0)      { W = gdW; a = gdas; o = wds; N = 256; }
    else if (sel == 1) { W = gdW; a = gdad; o = wdd; N = 256; }
    else if (sel == 2) { W = g1W; a = g1as; o = w1s; N = 1024; }
    else               { W = g1W; a = g1ad; o = w1d; N = 1024; }
    float s = 0.f;
    for (int n = t; n < N; n += 256) s += W[(long)k * N + n] * a[n];
#pragma unroll
    for (int off = 32; off; off >>= 1) s += __shfl_down(s, off);
    __shared__ float ls[4];
    if ((t & 63) == 0) ls[t >> 6] = s;
    __syncthreads();
    if (t == 0) o[k] = ls[0] + ls[1] + ls[2] + ls[3];
}

// ---------------- GEMM via split-bf16 MFMA, 128x64 tile ---------------------
// r9 finding: 128x128 tile -> 0.6..2.5 blocks/CU (grid-limited latency bind).
// 128x64: LDS 30.7KB -> 5 blocks/CU; 2x block count; acc 32 VGPR.
// XCD swizzle kept (c0 FETCH 127->28MB, r8-verified).
template<int ACT, int ASPLIT, int OSPLIT>  // ACT: 0=none,1=relu,2=elu
__global__ __launch_bounds__(256, 4) void gemm2(
    const float* __restrict__ A,
    const unsigned short* __restrict__ Ah_g, const unsigned short* __restrict__ Al_g,
    const unsigned short* __restrict__ Bh_g, const unsigned short* __restrict__ Bl_g,
    const float* __restrict__ bias,
    float* __restrict__ C, unsigned short* __restrict__ Ch_g, unsigned short* __restrict__ Cl_g,
    int M, int K, int N, int Kp, int Cs)
{
    __shared__ unsigned short Ah[128][40];
    __shared__ unsigned short Al[128][40];
    __shared__ unsigned short Bh[64][40];
    __shared__ unsigned short Bl[64][40];
    const int tid = threadIdx.x;
    const int wave = tid >> 6, lane = tid & 63;
    const int lm = lane & 15, lq = lane >> 4;
    const int wm = (wave & 1) << 6;        // m-half: 0 / 64
    const int wn = (wave >> 1) << 5;       // n-half: 0 / 32
    // ---- XCD swizzle (bijective over padded grid) ----
    const int nx = gridDim.x;
    const int lin = blockIdx.y * nx + blockIdx.x;
    const int sup = lin / (8 * nx);
    const int wit = lin - sup * 8 * nx;
    const int rowb = sup * 8 + (wit & 7);
    const int nb = wit >> 3;
    const int m0 = rowb * 128, n0 = nb * 64;
    if (m0 >= M) return;   // padded row-band

    floatx4 acc[4][2];
    floatx4 zero = {0.f, 0.f, 0.f, 0.f};
#pragma unroll
    for (int i = 0; i < 4; ++i)
#pragma unroll
        for (int j = 0; j < 2; ++j) acc[i][j] = zero;

    const bool k4 = (K & 3) == 0;
    const int arow = tid >> 1, ahalf = tid & 1;   // A staging: 128 rows x 2 halves
    const int brow = tid >> 2, bseg = tid & 3;    // B staging: 64 rows x 4 segs

    for (int k0 = 0; k0 < K; k0 += 32) {
        if (ASPLIT) {
            long ab = (long)(m0 + arow) * K + k0 + ahalf * 16;
            uint4 a0 = *(const uint4*)(Ah_g + ab);
            uint4 a1 = *(const uint4*)(Ah_g + ab + 8);
            *(uint4*)&Ah[arow][ahalf * 16] = a0;
            *(uint4*)&Ah[arow][ahalf * 16 + 8] = a1;
            uint4 b0 = *(const uint4*)(Al_g + ab);
            uint4 b1 = *(const uint4*)(Al_g + ab + 8);
            *(uint4*)&Al[arow][ahalf * 16] = b0;
            *(uint4*)&Al[arow][ahalf * 16 + 8] = b1;
        } else {
#pragma unroll
            for (int it = 0; it < 4; ++it) {
                int slot = tid + it * 256;
                int row = slot >> 3, kq = slot & 7;
                int gm = m0 + row, kb = k0 + kq * 4;
                float v0 = 0.f, v1 = 0.f, v2 = 0.f, v3 = 0.f;
                if (gm < M) {
                    if (k4 && kb + 4 <= K) {
                        float4 t = *(const float4*)(A + (long)gm * K + kb);
                        v0 = t.x; v1 = t.y; v2 = t.z; v3 = t.w;
                    } else {
                        if (kb + 0 < K) v0 = A[(long)gm * K + kb + 0];
                        if (kb + 1 < K) v1 = A[(long)gm * K + kb + 1];
                        if (kb + 2 < K) v2 = A[(long)gm * K + kb + 2];
                        if (kb + 3 < K) v3 = A[(long)gm * K + kb + 3];
                    }
                }
                unsigned short h0 = f2bf(v0), h1 = f2bf(v1), h2 = f2bf(v2), h3 = f2bf(v3);
                unsigned short l0 = f2bf(v0 - bf2f(h0)), l1 = f2bf(v1 - bf2f(h1));
                unsigned short l2 = f2bf(v2 - bf2f(h2)), l3 = f2bf(v3 - bf2f(h3));
                uint2 ph = {(unsigned)h0 | ((unsigned)h1 << 16), (unsigned)h2 | ((unsigned)h3 << 16)};
                uint2 pl = {(unsigned)l0 | ((unsigned)l1 << 16), (unsigned)l2 | ((unsigned)l3 << 16)};
                *(uint2*)&Ah[row][kq * 4] = ph;
                *(uint2*)&Al[row][kq * 4] = pl;
            }
        }
        // ---- stage B tile [64n][32k]: one uint4 per plane per thread ----
        {
            long bb = (long)(n0 + brow) * Kp + k0 + bseg * 8;
            *(uint4*)&Bh[brow][bseg * 8] = *(const uint4*)(Bh_g + bb);
            *(uint4*)&Bl[brow][bseg * 8] = *(const uint4*)(Bl_g + bb);
        }
        __syncthreads();
        short8 fah[4], fal[4], fbh[2], fbl[2];
#pragma unroll
        for (int i = 0; i < 4; ++i) {
            fah[i] = *(const short8*)&Ah[wm + i * 16 + lm][lq * 8];
            fal[i] = *(const short8*)&Al[wm + i * 16 + lm][lq * 8];
        }
#pragma unroll
        for (int j = 0; j < 2; ++j) {
            fbh[j] = *(const short8*)&Bh[wn + j * 16 + lm][lq * 8];
            fbl[j] = *(const short8*)&Bl[wn + j * 16 + lm][lq * 8];
        }
#pragma unroll
        for (int i = 0; i < 4; ++i)
#pragma unroll
            for (int j = 0; j < 2; ++j) {
                acc[i][j] = __builtin_amdgcn_mfma_f32_16x16x32_bf16(fah[i], fbh[j], acc[i][j], 0, 0, 0);
                acc[i][j] = __builtin_amdgcn_mfma_f32_16x16x32_bf16(fal[i], fbh[j], acc[i][j], 0, 0, 0);
                acc[i][j] = __builtin_amdgcn_mfma_f32_16x16x32_bf16(fah[i], fbl[j], acc[i][j], 0, 0, 0);
            }
        __syncthreads();
    }
    // ---- epilogue: C/D layout col=lane&15, row=quad*4+reg (m89-verified) ----
#pragma unroll
    for (int j = 0; j < 2; ++j) {
        int gn = n0 + wn + j * 16 + lm;
        float bv = bias ? bias[gn] : 0.f;
#pragma unroll
        for (int i = 0; i < 4; ++i) {
#pragma unroll
            for (int r = 0; r < 4; ++r) {
                int gm = m0 + wm + i * 16 + lq * 4 + r;
                if (gm < M) {
                    float v = acc[i][j][r] + bv;
                    if (ACT == 1) v = fmaxf(v, 0.f);
                    if (ACT == 2) v = v > 0.f ? v : expm1f(v);
                    if (OSPLIT) {
                        long o = (long)gm * Cs + gn;
                        unsigned short h = f2bf(v);
                        Ch_g[o] = h;
                        Cl_g[o] = f2bf(v - bf2f(h));
                    } else {
                        C[(long)gm * N + gn] = v;
                    }
                }
            }
        }
    }
}

// ---------------- per-node attention scalars (F=256) ----------------
__global__ __launch_bounds__(256) void att_scalars(
    const float* __restrict__ x, const float* __restrict__ avs,
    const float* __restrict__ avd, float* __restrict__ outs,
    float* __restrict__ outd, int F)
{
    const int i = blockIdx.x;
    const int t = threadIdx.x;
    float ps = 0.f, pd = 0.f;
    for (int f = t; f < F; f += 256) {
        float v = x[(long)i * F + f];
        ps += v * avs[f];
        pd += v * avd[f];
    }
#pragma unroll
    for (int off = 32; off; off >>= 1) {
        ps += __shfl_down(ps, off);
        pd += __shfl_down(pd, off);
    }
    __shared__ float ls[4], ld[4];
    int lane = t & 63, w = t >> 6;
    if (lane == 0) { ls[w] = ps; ld[w] = pd; }
    __syncthreads();
    if (t == 0) {
        outs[i] = ls[0] + ls[1] + ls[2] + ls[3];
        outd[i] = ld[0] + ld[1] + ld[2] + ld[3];
    }
}

// ---------------------------- CSR build (by dst) ----------------------------
__global__ __launch_bounds__(256) void hist_kernel(
    const int* __restrict__ dst, int* __restrict__ cnt, int E, int n)
{
    int t = blockIdx.x * 256 + threadIdx.x;
    if (t >= E + n) return;
    int d = t < E ? dst[t] : (t - E);
    atomicAdd(&cnt[d], 1);
}

#define SCAN_T 1024
__global__ __launch_bounds__(SCAN_T) void scan_kernel(
    const int* __restrict__ cnt, int* __restrict__ off,
    int* __restrict__ cursor, int n)
{
    __shared__ int sums[SCAN_T];
    int t = threadIdx.x;
    int chunk = (n + SCAN_T - 1) / SCAN_T;
    int lo = t * chunk, hi = min(lo + chunk, n);
    int s = 0;
    for (int i = lo; i < hi; ++i) s += cnt[i];
    sums[t] = s;
    __syncthreads();
    for (int d = 1; d < SCAN_T; d <<= 1) {
        int v = (t >= d) ? sums[t - d] : 0;
        __syncthreads();
        sums[t] += v;
        __syncthreads();
    }
    int run = sums[t] - s;
    for (int i = lo; i < hi; ++i) {
        off[i] = run;
        cursor[i] = run;
        run += cnt[i];
    }
    if (t == SCAN_T - 1) off[n] = sums[SCAN_T - 1];
}

__global__ __launch_bounds__(256) void scatter_kernel(
    const int* __restrict__ src, const int* __restrict__ dst,
    int* __restrict__ cursor, int* __restrict__ ebuf, int E, int n)
{
    int t = blockIdx.x * 256 + threadIdx.x;
    if (t >= E + n) return;
    int s = t < E ? src[t] : (t - E);
    int d = t < E ? dst[t] : (t - E);
    int pos = atomicAdd(&cursor[d], 1);
    ebuf[pos] = s;
}

// ------------- fused softmax + aggregate, F=256 fixed -----------------------
// One block per OUTPUT ROW. dmap: if non-null, dst node = dmap[blockIdx.x]
// (batch-sparse mode). EPI 0: bf16 hi/lo split planes. EPI 1: fp32 bias+relu.
template<int EPI>
__global__ __launch_bounds__(256) void gat_agg2(
    const int* __restrict__ off, const int* __restrict__ ebuf,
    const float* __restrict__ as_, const float* __restrict__ ad_,
    const float* __restrict__ x, const float* __restrict__ bias,
    const int* __restrict__ dmap,
    float* __restrict__ outF, unsigned short* __restrict__ outH,
    unsigned short* __restrict__ outL)
{
    __shared__ float sacc[4][256];
    __shared__ int   sS[128];
    __shared__ float sE[128];
    __shared__ float sred[8];
    int d = dmap ? dmap[blockIdx.x] : blockIdx.x;
    int tid = threadIdx.x;
    int w = tid >> 6, lane = tid & 63;
    int lo = off[d], hi = off[d + 1], ne = hi - lo;
    float adv = ad_[d];
    const float* xb = x + lane * 4;
    float4 acc0 = {0.f, 0.f, 0.f, 0.f}, acc1 = {0.f, 0.f, 0.f, 0.f};
    float psum = 0.f;

    if (ne <= 128) {
        if (tid < ne) {
            int s = ebuf[lo + tid];
            sS[tid] = s;
            sE[tid] = lrelu(as_[s] + adv);
        }
        __syncthreads();
        float m = (tid < ne) ? sE[tid] : -INFINITY;
#pragma unroll
        for (int o = 32; o; o >>= 1) m = fmaxf(m, __shfl_xor(m, o));
        if (lane == 0) sred[w] = m;
        __syncthreads();
        m = fmaxf(fmaxf(sred[0], sred[1]), fmaxf(sred[2], sred[3]));
        if (tid < ne) sE[tid] = expf(sE[tid] - m);
        __syncthreads();
        int i = w;
        for (; i + 4 < ne; i += 8) {
            int s0 = sS[i], s1 = sS[i + 4];
            float e0 = sE[i], e1 = sE[i + 4];
            float4 v0 = *(const float4*)(xb + (long)s0 * 256);
            float4 v1 = *(const float4*)(xb + (long)s1 * 256);
            psum += e0; psum += e1;
            acc0.x = fmaf(e0, v0.x, acc0.x); acc0.y = fmaf(e0, v0.y, acc0.y);
            acc0.z = fmaf(e0, v0.z, acc0.z); acc0.w = fmaf(e0, v0.w, acc0.w);
            acc1.x = fmaf(e1, v1.x, acc1.x); acc1.y = fmaf(e1, v1.y, acc1.y);
            acc1.z = fmaf(e1, v1.z, acc1.z); acc1.w = fmaf(e1, v1.w, acc1.w);
        }
        if (i < ne) {
            int s0 = sS[i];
            float e0 = sE[i];
            float4 v0 = *(const float4*)(xb + (long)s0 * 256);
            psum += e0;
            acc0.x = fmaf(e0, v0.x, acc0.x); acc0.y = fmaf(e0, v0.y, acc0.y);
            acc0.z = fmaf(e0, v0.z, acc0.z); acc0.w = fmaf(e0, v0.w, acc0.w);
        }
    } else {
        float m = -INFINITY;
        for (int p = lo + tid; p < hi; p += 256)
            m = fmaxf(m, lrelu(as_[ebuf[p]] + adv));
#pragma unroll
        for (int o = 32; o; o >>= 1) m = fmaxf(m, __shfl_xor(m, o));
        if (lane == 0) sred[w] = m;
        __syncthreads();
        m = fmaxf(fmaxf(sred[0], sred[1]), fmaxf(sred[2], sred[3]));
        for (int c = lo; c < hi; c += 128) {
            int cn = min(128, hi - c);
            __syncthreads();
            if (tid < cn) {
                int s = ebuf[c + tid];
                sS[tid] = s;
                sE[tid] = expf(lrelu(as_[s] + adv) - m);
            }
            __syncthreads();
            int i = w;
            for (; i + 4 < cn; i += 8) {
                int s0 = sS[i], s1 = sS[i + 4];
                float e0 = sE[i], e1 = sE[i + 4];
                float4 v0 = *(const float4*)(xb + (long)s0 * 256);
                float4 v1 = *(const float4*)(xb + (long)s1 * 256);
                psum += e0; psum += e1;
                acc0.x = fmaf(e0, v0.x, acc0.x); acc0.y = fmaf(e0, v0.y, acc0.y);
                acc0.z = fmaf(e0, v0.z, acc0.z); acc0.w = fmaf(e0, v0.w, acc0.w);
                acc1.x = fmaf(e1, v1.x, acc1.x); acc1.y = fmaf(e1, v1.y, acc1.y);
                acc1.z = fmaf(e1, v1.z, acc1.z); acc1.w = fmaf(e1, v1.w, acc1.w);
            }
            if (i < cn) {
                int s0 = sS[i];
                float e0 = sE[i];
                float4 v0 = *(const float4*)(xb + (long)s0 * 256);
                psum += e0;
                acc0.x = fmaf(e0, v0.x, acc0.x); acc0.y = fmaf(e0, v0.y, acc0.y);
                acc0.z = fmaf(e0, v0.z, acc0.z); acc0.w = fmaf(e0, v0.w, acc0.w);
            }
        }
    }
    acc0.x += acc1.x; acc0.y += acc1.y; acc0.z += acc1.z; acc0.w += acc1.w;
    if (lane == 0) sred[4 + w] = psum;
    *(float4*)&sacc[w][lane * 4] = acc0;
    __syncthreads();
    float inv = 1.f / (sred[4] + sred[5] + sred[6] + sred[7]);
    float v = (sacc[0][tid] + sacc[1][tid] + sacc[2][tid] + sacc[3][tid]) * inv;
    long o = (long)blockIdx.x * 256 + tid;
    if (EPI == 1) {
        outF[o] = fmaxf(v + bias[tid], 0.f);
    } else {
        unsigned short h = f2bf(v);
        outH[o] = h;
        outL[o] = f2bf(v - bf2f(h));
    }
}

// comb right half: comb[i][256+t] = split(cfin[cidx[i]][t])
__global__ __launch_bounds__(256) void gather_cell_split(
    const float* __restrict__ cfin, const int* __restrict__ cidx,
    unsigned short* __restrict__ combH, unsigned short* __restrict__ combL)
{
    int i = blockIdx.x;
    int t = threadIdx.x;
    float v = cfin[(long)cidx[i] * 256 + t];
    long b = (long)i * 512 + 256 + t;
    unsigned short h = f2bf(v);
    combH[b] = h;
    combL[b] = f2bf(v - bf2f(h));
}

// out[i] = h[i] . w + b[0]
__global__ __launch_bounds__(256) void head_final_kernel(
    const float* __restrict__ h, const float* __restrict__ w,
    const float* __restrict__ b, float* __restrict__ out, int M)
{
    int gw = blockIdx.x * 4 + (threadIdx.x >> 6);
    int lane = threadIdx.x & 63;
    if (gw >= M) return;
    const float* row = h + (long)gw * 512;
    float s = 0.f;
#pragma unroll
    for (int f = lane; f < 512; f += 64) s += row[f] * w[f];
#pragma unroll
    for (int off = 32; off; off >>= 1) s += __shfl_down(s, off);
    if (lane == 0) out[gw] = s + b[0];
}

// ------------------------------ orchestration -------------------------------
// 128x64 tiles; grid padded so XCD swizzle's 8-row-band groups stay bijective
static inline dim3 mfma_grid(int M, int N) {
    int ny = (M + 127) / 128;
    ny = (ny + 7) & ~7;
    return dim3(N / 64, ny);
}

extern "C" void kernel_launch(void* const* d_in, const int* in_sizes, int n_in,
                              void* d_out, int out_size, void* d_ws, size_t ws_size,
                              hipStream_t stream)
{
    const float* drug_x = (const float*)d_in[0];
    const float* cell_x = (const float*)d_in[1];
    const int* d_ei = (const int*)d_in[2];
    const int* c_ei = (const int*)d_in[3];
    const int* d_idx = (const int*)d_in[4];
    const int* c_idx = (const int*)d_in[5];
    const float* dW1 = (const float*)d_in[6];
    const float* db1 = (const float*)d_in[7];
    const float* cW1 = (const float*)d_in[8];
    const float* cb1 = (const float*)d_in[9];
    const float* cW2 = (const float*)d_in[10];
    const float* cb2 = (const float*)d_in[11];
    const float* gdW = (const float*)d_in[12];
    const float* gdas = (const float*)d_in[13];
    const float* gdad = (const float*)d_in[14];
    const float* gdb = (const float*)d_in[15];
    const float* g1W = (const float*)d_in[16];
    const float* g1as = (const float*)d_in[17];
    const float* g1ad = (const float*)d_in[18];
    const float* g1b = (const float*)d_in[19];
    const float* g2W = (const float*)d_in[20];
    const float* g2as = (const float*)d_in[21];
    const float* g2ad = (const float*)d_in[22];
    const float* g2b = (const float*)d_in[23];
    const float* rW1 = (const float*)d_in[24];
    const float* rb1 = (const float*)d_in[25];
    const float* rW2 = (const float*)d_in[26];
    const float* rb2 = (const float*)d_in[27];
    const float* rW3 = (const float*)d_in[28];
    const float* rb3 = (const float*)d_in[29];

    const int ND = in_sizes[0] / 128;     // 50000
    const int NC = in_sizes[1] / 735;     // 10000
    const int ED = in_sizes[2] / 2;       // 800000
    const int EC = in_sizes[3] / 2;       // 160000
    const int NB = in_sizes[4];           // 16384

    const int* d_src = d_ei;
    const int* d_dst = d_ei + ED;
    const int* c_src = c_ei;
    const int* c_dst = c_ei + EC;

    const size_t MB = 1ull << 20;
    const size_t KB = 1024;
    char* ws = (char*)d_ws;

    // ---- weight split region [0, 9MB) ----
    size_t wo = 0;
    auto walloc = [&](size_t elems) -> unsigned short* {
        unsigned short* p = (unsigned short*)(ws + wo);
        wo += ((elems * 2 + 255) & ~(size_t)255);
        return p;
    };
    unsigned short* dW1h = walloc(256 * 128);  unsigned short* dW1l = walloc(256 * 128);
    unsigned short* cW1h = walloc(1024 * 736); unsigned short* cW1l = walloc(1024 * 736);
    unsigned short* cW2h = walloc(256 * 1024); unsigned short* cW2l = walloc(256 * 1024);
    unsigned short* gdWh = walloc(256 * 256);  unsigned short* gdWl = walloc(256 * 256);
    unsigned short* g1Wh = walloc(1024 * 256); unsigned short* g1Wl = walloc(1024 * 256);
    unsigned short* g2Wh = walloc(256 * 1024); unsigned short* g2Wl = walloc(256 * 1024);
    unsigned short* rW1h = walloc(512 * 512);  unsigned short* rW1l = walloc(512 * 512);
    unsigned short* rW2h = walloc(512 * 512);  unsigned short* rW2l = walloc(512 * 512);

    // ---- small scratch [9, 16MB) ----
    float* wa_ds  = (float*)(ws + 9 * MB);
    float* wa_dd  = (float*)(ws + 9 * MB + 4 * KB);
    float* wa_c1s = (float*)(ws + 9 * MB + 8 * KB);
    float* wa_c1d = (float*)(ws + 9 * MB + 12 * KB);
    float* cas    = (float*)(ws + 9 * MB + 64 * KB);
    float* cad    = (float*)(ws + 9 * MB + 128 * KB);
    int*   coff   = (int*)(ws + 9 * MB + 192 * KB);
    int*   ccur   = (int*)(ws + 9 * MB + 256 * KB);
    int*   ccnt   = (int*)(ws + 9 * MB + 320 * KB);
    int*   cebuf  = (int*)(ws + 10 * MB);              // EC+NC ints
    float* das    = (float*)(ws + 11 * MB);
    float* dad    = (float*)(ws + 11 * MB + 256 * KB);
    int*   doff   = (int*)(ws + 11 * MB + 512 * KB);
    int*   dcur   = (int*)(ws + 11 * MB + 768 * KB);
    int*   dcnt   = (int*)(ws + 12 * MB);
    int*   debuf  = (int*)(ws + 12 * MB + 256 * KB);   // ED+ND ints -> ends ~15.7MB

    // ---- big buffers (liveness-checked) ----
    float* dbuf  = (float*)(ws + 16 * MB);                    // d0 [ND,256] [16,65)
    unsigned short* aggdh = (unsigned short*)(ws + 66 * MB);  // [NB,256] [66,74)
    unsigned short* aggdl = (unsigned short*)(ws + 75 * MB);  // [75,83)
    unsigned short* combh = (unsigned short*)(ws + 84 * MB);  // [NB,512] [84,100)
    unsigned short* combl = (unsigned short*)(ws + 101 * MB); // [101,117)
    unsigned short* c0h = (unsigned short*)(ws + 16 * MB);    // [10112,1024] [16,36)  (dbuf dead)
    unsigned short* c0l = (unsigned short*)(ws + 36 * MB);    // [36,56)
    float* c1b   = (float*)(ws + 118 * MB);                   // [NC,256] [118,128)
    unsigned short* aggch = (unsigned short*)(ws + 129 * MB); // [10112,256] [129,134.1)
    unsigned short* aggcl = (unsigned short*)(ws + 135 * MB); // [135,140.1)
    unsigned short* c2h = (unsigned short*)(ws + 16 * MB);    // [16,36)  (c0 dead)
    unsigned short* c2l = (unsigned short*)(ws + 36 * MB);    // [36,56)
    float* xc2   = (float*)(ws + 118 * MB);                   // [118,128) (c1 dead)
    float* cfin  = (float*)(ws + 141 * MB);                   // [141,151)
    unsigned short* h1h = (unsigned short*)(ws + 16 * MB);    // [NB,512] [16,32) (c2 dead)
    unsigned short* h1l = (unsigned short*)(ws + 33 * MB);    // [33,49)
    float* h2b   = (float*)(ws + 50 * MB);                    // [NB,512] fp32 [50,82)

    // ================= fused prepass: 8 splits + 4 matvecs ===================
    SJobs js;
    js.j[0] = {dW1, dW1h, dW1l, 128, 256, 128, 0};
    js.j[1] = {cW1, cW1h, cW1l, 735, 1024, 736, 32};
    js.j[2] = {cW2, cW2h, cW2l, 1024, 256, 1024, 768};
    js.j[3] = {gdW, gdWh, gdWl, 256, 256, 256, 1024};
    js.j[4] = {g1W, g1Wh, g1Wl, 256, 1024, 256, 1088};
    js.j[5] = {g2W, g2Wh, g2Wl, 1024, 256, 1024, 1344};
    js.j[6] = {rW1, rW1h, rW1l, 512, 512, 512, 1600};
    js.j[7] = {rW2, rW2h, rW2l, 512, 512, 512, 1856};
    split_transpose_multi<<<2112, 256, 0, stream>>>(js);
    matvec4<<<1024, 256, 0, stream>>>(gdW, gdas, gdad, wa_ds, wa_dd,
                                      g1W, g1as, g1ad, wa_c1s, wa_c1d);

    // ======================= drug path (batch-sparse) =======================
    // d0 = relu(drug_x @ dW1 + db1) -> fp32, full ND (any node can be a src)
    gemm2<1, 0, 0><<<mfma_grid(ND, 256), 256, 0, stream>>>(
        drug_x, nullptr, nullptr, dW1h, dW1l, db1, dbuf, nullptr, nullptr,
        ND, 128, 256, 128, 256);
    att_scalars<<<ND, 256, 0, stream>>>(dbuf, wa_ds, wa_dd, das, dad, 256);
    hipMemsetAsync(dcnt, 0, (size_t)ND * 4, stream);
    {
        int tot = ED + ND;
        hist_kernel<<<(tot + 255) / 256, 256, 0, stream>>>(d_dst, dcnt, ED, ND);
        scan_kernel<<<1, SCAN_T, 0, stream>>>(dcnt, doff, dcur, ND);
        scatter_kernel<<<(tot + 255) / 256, 256, 0, stream>>>(d_src, d_dst, dcur, debuf, ED, ND);
        // only the NB batch rows: block i aggregates dst node didx[i]
        gat_agg2<0><<<NB, 256, 0, stream>>>(doff, debuf, das, dad, dbuf, nullptr,
                                            d_idx, nullptr, aggdh, aggdl);
    }
    // comb left half = relu(aggd_batch @ gdW + gdb) as split planes (stride 512)
    gemm2<1, 1, 1><<<mfma_grid(NB, 256), 256, 0, stream>>>(
        nullptr, aggdh, aggdl, gdWh, gdWl, gdb, nullptr, combh, combl,
        NB, 256, 256, 256, 512);

    // ======================= cell path =======================
    gemm2<1, 0, 1><<<mfma_grid(NC, 1024), 256, 0, stream>>>(
        cell_x, nullptr, nullptr, cW1h, cW1l, cb1, nullptr, c0h, c0l,
        NC, 735, 1024, 736, 1024);
    gemm2<1, 1, 0><<<mfma_grid(NC, 256), 256, 0, stream>>>(
        nullptr, c0h, c0l, cW2h, cW2l, cb2, c1b, nullptr, nullptr,
        NC, 1024, 256, 1024, 256);
    att_scalars<<<NC, 256, 0, stream>>>(c1b, wa_c1s, wa_c1d, cas, cad, 256);
    hipMemsetAsync(ccnt, 0, (size_t)NC * 4, stream);
    {
        int tot = EC + NC;
        hist_kernel<<<(tot + 255) / 256, 256, 0, stream>>>(c_dst, ccnt, EC, NC);
        scan_kernel<<<1, SCAN_T, 0, stream>>>(ccnt, coff, ccur, NC);
        scatter_kernel<<<(tot + 255) / 256, 256, 0, stream>>>(c_src, c_dst, ccur, cebuf, EC, NC);
        gat_agg2<0><<<NC, 256, 0, stream>>>(coff, cebuf, cas, cad, c1b, nullptr,
                                            nullptr, nullptr, aggch, aggcl);
    }
    gemm2<1, 1, 1><<<mfma_grid(NC, 1024), 256, 0, stream>>>(
        nullptr, aggch, aggcl, g1Wh, g1Wl, g1b, nullptr, c2h, c2l,
        NC, 256, 1024, 256, 1024);
    gemm2<0, 1, 0><<<mfma_grid(NC, 256), 256, 0, stream>>>(
        nullptr, c2h, c2l, g2Wh, g2Wl, nullptr, xc2, nullptr, nullptr,
        NC, 1024, 256, 1024, 256);
    att_scalars<<<NC, 256, 0, stream>>>(xc2, g2as, g2ad, cas, cad, 256);
    gat_agg2<1><<<NC, 256, 0, stream>>>(coff, cebuf, cas, cad, xc2, g2b,
                                        nullptr, cfin, nullptr, nullptr);

    // ======================= head =======================
    gather_cell_split<<<NB, 256, 0, stream>>>(cfin, c_idx, combh, combl);
    gemm2<2, 1, 1><<<mfma_grid(NB, 512), 256, 0, stream>>>(
        nullptr, combh, combl, rW1h, rW1l, rb1, nullptr, h1h, h1l,
        NB, 512, 512, 512, 512);
    gemm2<2, 1, 0><<<mfma_grid(NB, 512), 256, 0, stream>>>(
        nullptr, h1h, h1l, rW2h, rW2l, rb2, h2b, nullptr, nullptr,
        NB, 512, 512, 512, 512);
    head_final_kernel<<<(NB + 3) / 4, 256, 0, stream>>>(h2b, rW3, rb3, (float*)d_out, NB);
}

// Round 11
// 925.783 us; speedup vs baseline: 1.0422x; 1.0422x over previous
//
#include <hip/hip_runtime.h>
#include <math.h>

#define NEG_SLOPE 0.2f

typedef __attribute__((ext_vector_type(8))) short short8;
typedef __attribute__((ext_vector_type(4))) float floatx4;

// ---------------- fp32 <-> bf16 split helpers (RNE) ----------------
__device__ __forceinline__ unsigned short f2bf(float f) {
    unsigned u = __float_as_uint(f);
    u += 0x7fffu + ((u >> 16) & 1u);
    return (unsigned short)(u >> 16);
}
__device__ __forceinline__ float bf2f(unsigned short h) {
    return __uint_as_float((unsigned)h << 16);
}
__device__ __forceinline__ float lrelu(float v) {
    return v > 0.f ? v : NEG_SLOPE * v;
}

// ---------------- fused weight pre-pass: 8 jobs in one launch ----------------
struct SJob { const float* W; unsigned short* Th; unsigned short* Tl; int K, N, Kp, base; };
struct SJobs { SJob j[8]; };

__global__ __launch_bounds__(256) void split_transpose_multi(SJobs js) {
    int t = blockIdx.x;
    int ji = 0;
#pragma unroll
    for (int q = 1; q < 8; ++q) if (t >= js.j[q].base) ji = q;
    const SJob jb = js.j[ji];
    int local = t - jb.base;
    int ntiles = jb.N / 32;
    int tn = local % ntiles, tk = local / ntiles;
    int k0 = tk * 32, n0 = tn * 32;
    __shared__ float tbuf[32][33];
    int c = threadIdx.x & 31, r = threadIdx.x >> 5;
    for (int rr = r; rr < 32; rr += 8) {
        int k = k0 + rr, n = n0 + c;
        tbuf[rr][c] = (k < jb.K && n < jb.N) ? jb.W[(long)k * jb.N + n] : 0.f;
    }
    __syncthreads();
    for (int rr = r; rr < 32; rr += 8) {
        int n = n0 + rr, k = k0 + c;
        if (n < jb.N && k < jb.Kp) {
            float v = tbuf[c][rr];
            unsigned short h = f2bf(v);
            jb.Th[(long)n * jb.Kp + k] = h;
            jb.Tl[(long)n * jb.Kp + k] = f2bf(v - bf2f(h));
        }
    }
}

// ---- 4 fused matvecs: wa[k] = sum_n W[k][n]*a[n] (k in [0,256) each) ----
__global__ __launch_bounds__(256) void matvec4(
    const float* __restrict__ gdW, const float* __restrict__ gdas, const float* __restrict__ gdad,
    float* __restrict__ wds, float* __restrict__ wdd,
    const float* __restrict__ g1W, const float* __restrict__ g1as, const float* __restrict__ g1ad,
    float* __restrict__ w1s, float* __restrict__ w1d)
{
    int b = blockIdx.x;
    int sel = b >> 8, k = b & 255, t = threadIdx.x;
    const float *W, *a; float* o; int N;
    if (sel == 0)      { W = gdW; a = gdas; o = wds; N = 256; }
    else if (sel == 1) { W = gdW; a = gdad; o = wdd; N = 256; }
    else if (sel == 2) { W = g1W; a = g1as; o = w1s; N = 1024; }
    else               { W = g1W; a = g1ad; o = w1d; N = 1024; }
    float s = 0.f;
    for (int n = t; n < N; n += 256) s += W[(long)k * N + n] * a[n];
#pragma unroll
    for (int off = 32; off; off >>= 1) s += __shfl_down(s, off);
    __shared__ float ls[4];
    if ((t & 63) == 0) ls[t >> 6] = s;
    __syncthreads();
    if (t == 0) o[k] = ls[0] + ls[1] + ls[2] + ls[3];
}

// ---------------- GEMM via split-bf16 MFMA, 128x128 tile, 512 threads -------
// r10 lesson: 128x128 is the right tile; bottleneck is waves-in-flight.
// 8 waves/block, each owning a 64x32 quadrant (acc[4][2]=32 VGPR, ~110 regs
// total <= 128-cap from launch_bounds(512,4)) -> ~16 waves/CU at the same
// grid, double the latency hiding. XCD swizzle kept (c0 FETCH 127->28MB).
template<int ACT, int ASPLIT, int OSPLIT>  // ACT: 0=none,1=relu,2=elu
__global__ __launch_bounds__(512, 4) void gemm2(
    const float* __restrict__ A,
    const unsigned short* __restrict__ Ah_g, const unsigned short* __restrict__ Al_g,
    const unsigned short* __restrict__ Bh_g, const unsigned short* __restrict__ Bl_g,
    const float* __restrict__ bias,
    float* __restrict__ C, unsigned short* __restrict__ Ch_g, unsigned short* __restrict__ Cl_g,
    int M, int K, int N, int Kp, int Cs)
{
    __shared__ unsigned short Ah[128][40];
    __shared__ unsigned short Al[128][40];
    __shared__ unsigned short Bh[128][40];
    __shared__ unsigned short Bl[128][40];
    const int tid = threadIdx.x;
    const int wave = tid >> 6, lane = tid & 63;
    const int lm = lane & 15, lq = lane >> 4;
    const int wm = (wave & 1) << 6;      // m-half: 0 / 64
    const int wn = (wave >> 1) << 5;     // n-quarter: 0 / 32 / 64 / 96
    // ---- XCD swizzle (bijective over padded grid) ----
    const int nx = gridDim.x;
    const int lin = blockIdx.y * nx + blockIdx.x;
    const int sup = lin / (8 * nx);
    const int wit = lin - sup * 8 * nx;
    const int rowb = sup * 8 + (wit & 7);
    const int nb = wit >> 3;
    const int m0 = rowb * 128, n0 = nb * 128;
    if (m0 >= M) return;   // padded row-band

    floatx4 acc[4][2];
    floatx4 zero = {0.f, 0.f, 0.f, 0.f};
#pragma unroll
    for (int i = 0; i < 4; ++i)
#pragma unroll
        for (int j = 0; j < 2; ++j) acc[i][j] = zero;

    const bool k4 = (K & 3) == 0;
    const int srow = tid >> 2, sseg = tid & 3;  // staging: 128 rows x 4 segs x 8 ushorts

    for (int k0 = 0; k0 < K; k0 += 32) {
        if (ASPLIT) {
            long ab = (long)(m0 + srow) * K + k0 + sseg * 8;
            *(uint4*)&Ah[srow][sseg * 8] = *(const uint4*)(Ah_g + ab);
            *(uint4*)&Al[srow][sseg * 8] = *(const uint4*)(Al_g + ab);
        } else {
#pragma unroll
            for (int it = 0; it < 2; ++it) {
                int slot = tid + it * 512;
                int row = slot >> 3, kq = slot & 7;
                int gm = m0 + row, kb = k0 + kq * 4;
                float v0 = 0.f, v1 = 0.f, v2 = 0.f, v3 = 0.f;
                if (gm < M) {
                    if (k4 && kb + 4 <= K) {
                        float4 t = *(const float4*)(A + (long)gm * K + kb);
                        v0 = t.x; v1 = t.y; v2 = t.z; v3 = t.w;
                    } else {
                        if (kb + 0 < K) v0 = A[(long)gm * K + kb + 0];
                        if (kb + 1 < K) v1 = A[(long)gm * K + kb + 1];
                        if (kb + 2 < K) v2 = A[(long)gm * K + kb + 2];
                        if (kb + 3 < K) v3 = A[(long)gm * K + kb + 3];
                    }
                }
                unsigned short h0 = f2bf(v0), h1 = f2bf(v1), h2 = f2bf(v2), h3 = f2bf(v3);
                unsigned short l0 = f2bf(v0 - bf2f(h0)), l1 = f2bf(v1 - bf2f(h1));
                unsigned short l2 = f2bf(v2 - bf2f(h2)), l3 = f2bf(v3 - bf2f(h3));
                uint2 ph = {(unsigned)h0 | ((unsigned)h1 << 16), (unsigned)h2 | ((unsigned)h3 << 16)};
                uint2 pl = {(unsigned)l0 | ((unsigned)l1 << 16), (unsigned)l2 | ((unsigned)l3 << 16)};
                *(uint2*)&Ah[row][kq * 4] = ph;
                *(uint2*)&Al[row][kq * 4] = pl;
            }
        }
        // ---- stage B tile [128n][32k]: one uint4 per plane per thread ----
        {
            long bb = (long)(n0 + srow) * Kp + k0 + sseg * 8;
            *(uint4*)&Bh[srow][sseg * 8] = *(const uint4*)(Bh_g + bb);
            *(uint4*)&Bl[srow][sseg * 8] = *(const uint4*)(Bl_g + bb);
        }
        __syncthreads();
        short8 fah[4], fal[4], fbh[2], fbl[2];
#pragma unroll
        for (int i = 0; i < 4; ++i) {
            fah[i] = *(const short8*)&Ah[wm + i * 16 + lm][lq * 8];
            fal[i] = *(const short8*)&Al[wm + i * 16 + lm][lq * 8];
        }
#pragma unroll
        for (int j = 0; j < 2; ++j) {
            fbh[j] = *(const short8*)&Bh[wn + j * 16 + lm][lq * 8];
            fbl[j] = *(const short8*)&Bl[wn + j * 16 + lm][lq * 8];
        }
#pragma unroll
        for (int i = 0; i < 4; ++i)
#pragma unroll
            for (int j = 0; j < 2; ++j) {
                acc[i][j] = __builtin_amdgcn_mfma_f32_16x16x32_bf16(fah[i], fbh[j], acc[i][j], 0, 0, 0);
                acc[i][j] = __builtin_amdgcn_mfma_f32_16x16x32_bf16(fal[i], fbh[j], acc[i][j], 0, 0, 0);
                acc[i][j] = __builtin_amdgcn_mfma_f32_16x16x32_bf16(fah[i], fbl[j], acc[i][j], 0, 0, 0);
            }
        __syncthreads();
    }
    // ---- epilogue: C/D layout col=lane&15, row=quad*4+reg (m89-verified) ----
#pragma unroll
    for (int j = 0; j < 2; ++j) {
        int gn = n0 + wn + j * 16 + lm;
        float bv = bias ? bias[gn] : 0.f;
#pragma unroll
        for (int i = 0; i < 4; ++i) {
#pragma unroll
            for (int r = 0; r < 4; ++r) {
                int gm = m0 + wm + i * 16 + lq * 4 + r;
                if (gm < M) {
                    float v = acc[i][j][r] + bv;
                    if (ACT == 1) v = fmaxf(v, 0.f);
                    if (ACT == 2) v = v > 0.f ? v : expm1f(v);
                    if (OSPLIT) {
                        long o = (long)gm * Cs + gn;
                        unsigned short h = f2bf(v);
                        Ch_g[o] = h;
                        Cl_g[o] = f2bf(v - bf2f(h));
                    } else {
                        C[(long)gm * N + gn] = v;
                    }
                }
            }
        }
    }
}

// ---------------- per-node attention scalars (F=256) ----------------
__global__ __launch_bounds__(256) void att_scalars(
    const float* __restrict__ x, const float* __restrict__ avs,
    const float* __restrict__ avd, float* __restrict__ outs,
    float* __restrict__ outd, int F)
{
    const int i = blockIdx.x;
    const int t = threadIdx.x;
    float ps = 0.f, pd = 0.f;
    for (int f = t; f < F; f += 256) {
        float v = x[(long)i * F + f];
        ps += v * avs[f];
        pd += v * avd[f];
    }
#pragma unroll
    for (int off = 32; off; off >>= 1) {
        ps += __shfl_down(ps, off);
        pd += __shfl_down(pd, off);
    }
    __shared__ float ls[4], ld[4];
    int lane = t & 63, w = t >> 6;
    if (lane == 0) { ls[w] = ps; ld[w] = pd; }
    __syncthreads();
    if (t == 0) {
        outs[i] = ls[0] + ls[1] + ls[2] + ls[3];
        outd[i] = ld[0] + ld[1] + ld[2] + ld[3];
    }
}

// ---------------------------- CSR build (by dst) ----------------------------
__global__ __launch_bounds__(256) void hist_kernel(
    const int* __restrict__ dst, int* __restrict__ cnt, int E, int n)
{
    int t = blockIdx.x * 256 + threadIdx.x;
    if (t >= E + n) return;
    int d = t < E ? dst[t] : (t - E);
    atomicAdd(&cnt[d], 1);
}

#define SCAN_T 1024
__global__ __launch_bounds__(SCAN_T) void scan_kernel(
    const int* __restrict__ cnt, int* __restrict__ off,
    int* __restrict__ cursor, int n)
{
    __shared__ int sums[SCAN_T];
    int t = threadIdx.x;
    int chunk = (n + SCAN_T - 1) / SCAN_T;
    int lo = t * chunk, hi = min(lo + chunk, n);
    int s = 0;
    for (int i = lo; i < hi; ++i) s += cnt[i];
    sums[t] = s;
    __syncthreads();
    for (int d = 1; d < SCAN_T; d <<= 1) {
        int v = (t >= d) ? sums[t - d] : 0;
        __syncthreads();
        sums[t] += v;
        __syncthreads();
    }
    int run = sums[t] - s;
    for (int i = lo; i < hi; ++i) {
        off[i] = run;
        cursor[i] = run;
        run += cnt[i];
    }
    if (t == SCAN_T - 1) off[n] = sums[SCAN_T - 1];
}

__global__ __launch_bounds__(256) void scatter_kernel(
    const int* __restrict__ src, const int* __restrict__ dst,
    int* __restrict__ cursor, int* __restrict__ ebuf, int E, int n)
{
    int t = blockIdx.x * 256 + threadIdx.x;
    if (t >= E + n) return;
    int s = t < E ? src[t] : (t - E);
    int d = t < E ? dst[t] : (t - E);
    int pos = atomicAdd(&cursor[d], 1);
    ebuf[pos] = s;
}

// ------------- fused softmax + aggregate, F=256 fixed -----------------------
// One block per OUTPUT ROW. dmap: if non-null, dst node = dmap[blockIdx.x]
// (batch-sparse mode). EPI 0: bf16 hi/lo split planes. EPI 1: fp32 bias+relu.
template<int EPI>
__global__ __launch_bounds__(256) void gat_agg2(
    const int* __restrict__ off, const int* __restrict__ ebuf,
    const float* __restrict__ as_, const float* __restrict__ ad_,
    const float* __restrict__ x, const float* __restrict__ bias,
    const int* __restrict__ dmap,
    float* __restrict__ outF, unsigned short* __restrict__ outH,
    unsigned short* __restrict__ outL)
{
    __shared__ float sacc[4][256];
    __shared__ int   sS[128];
    __shared__ float sE[128];
    __shared__ float sred[8];
    int d = dmap ? dmap[blockIdx.x] : blockIdx.x;
    int tid = threadIdx.x;
    int w = tid >> 6, lane = tid & 63;
    int lo = off[d], hi = off[d + 1], ne = hi - lo;
    float adv = ad_[d];
    const float* xb = x + lane * 4;
    float4 acc0 = {0.f, 0.f, 0.f, 0.f}, acc1 = {0.f, 0.f, 0.f, 0.f};
    float psum = 0.f;

    if (ne <= 128) {
        if (tid < ne) {
            int s = ebuf[lo + tid];
            sS[tid] = s;
            sE[tid] = lrelu(as_[s] + adv);
        }
        __syncthreads();
        float m = (tid < ne) ? sE[tid] : -INFINITY;
#pragma unroll
        for (int o = 32; o; o >>= 1) m = fmaxf(m, __shfl_xor(m, o));
        if (lane == 0) sred[w] = m;
        __syncthreads();
        m = fmaxf(fmaxf(sred[0], sred[1]), fmaxf(sred[2], sred[3]));
        if (tid < ne) sE[tid] = expf(sE[tid] - m);
        __syncthreads();
        int i = w;
        for (; i + 4 < ne; i += 8) {
            int s0 = sS[i], s1 = sS[i + 4];
            float e0 = sE[i], e1 = sE[i + 4];
            float4 v0 = *(const float4*)(xb + (long)s0 * 256);
            float4 v1 = *(const float4*)(xb + (long)s1 * 256);
            psum += e0; psum += e1;
            acc0.x = fmaf(e0, v0.x, acc0.x); acc0.y = fmaf(e0, v0.y, acc0.y);
            acc0.z = fmaf(e0, v0.z, acc0.z); acc0.w = fmaf(e0, v0.w, acc0.w);
            acc1.x = fmaf(e1, v1.x, acc1.x); acc1.y = fmaf(e1, v1.y, acc1.y);
            acc1.z = fmaf(e1, v1.z, acc1.z); acc1.w = fmaf(e1, v1.w, acc1.w);
        }
        if (i < ne) {
            int s0 = sS[i];
            float e0 = sE[i];
            float4 v0 = *(const float4*)(xb + (long)s0 * 256);
            psum += e0;
            acc0.x = fmaf(e0, v0.x, acc0.x); acc0.y = fmaf(e0, v0.y, acc0.y);
            acc0.z = fmaf(e0, v0.z, acc0.z); acc0.w = fmaf(e0, v0.w, acc0.w);
        }
    } else {
        float m = -INFINITY;
        for (int p = lo + tid; p < hi; p += 256)
            m = fmaxf(m, lrelu(as_[ebuf[p]] + adv));
#pragma unroll
        for (int o = 32; o; o >>= 1) m = fmaxf(m, __shfl_xor(m, o));
        if (lane == 0) sred[w] = m;
        __syncthreads();
        m = fmaxf(fmaxf(sred[0], sred[1]), fmaxf(sred[2], sred[3]));
        for (int c = lo; c < hi; c += 128) {
            int cn = min(128, hi - c);
            __syncthreads();
            if (tid < cn) {
                int s = ebuf[c + tid];
                sS[tid] = s;
                sE[tid] = expf(lrelu(as_[s] + adv) - m);
            }
            __syncthreads();
            int i = w;
            for (; i + 4 < cn; i += 8) {
                int s0 = sS[i], s1 = sS[i + 4];
                float e0 = sE[i], e1 = sE[i + 4];
                float4 v0 = *(const float4*)(xb + (long)s0 * 256);
                float4 v1 = *(const float4*)(xb + (long)s1 * 256);
                psum += e0; psum += e1;
                acc0.x = fmaf(e0, v0.x, acc0.x); acc0.y = fmaf(e0, v0.y, acc0.y);
                acc0.z = fmaf(e0, v0.z, acc0.z); acc0.w = fmaf(e0, v0.w, acc0.w);
                acc1.x = fmaf(e1, v1.x, acc1.x); acc1.y = fmaf(e1, v1.y, acc1.y);
                acc1.z = fmaf(e1, v1.z, acc1.z); acc1.w = fmaf(e1, v1.w, acc1.w);
            }
            if (i < cn) {
                int s0 = sS[i];
                float e0 = sE[i];
                float4 v0 = *(const float4*)(xb + (long)s0 * 256);
                psum += e0;
                acc0.x = fmaf(e0, v0.x, acc0.x); acc0.y = fmaf(e0, v0.y, acc0.y);
                acc0.z = fmaf(e0, v0.z, acc0.z); acc0.w = fmaf(e0, v0.w, acc0.w);
            }
        }
    }
    acc0.x += acc1.x; acc0.y += acc1.y; acc0.z += acc1.z; acc0.w += acc1.w;
    if (lane == 0) sred[4 + w] = psum;
    *(float4*)&sacc[w][lane * 4] = acc0;
    __syncthreads();
    float inv = 1.f / (sred[4] + sred[5] + sred[6] + sred[7]);
    float v = (sacc[0][tid] + sacc[1][tid] + sacc[2][tid] + sacc[3][tid]) * inv;
    long o = (long)blockIdx.x * 256 + tid;
    if (EPI == 1) {
        outF[o] = fmaxf(v + bias[tid], 0.f);
    } else {
        unsigned short h = f2bf(v);
        outH[o] = h;
        outL[o] = f2bf(v - bf2f(h));
    }
}

// comb right half: comb[i][256+t] = split(cfin[cidx[i]][t])
__global__ __launch_bounds__(256) void gather_cell_split(
    const float* __restrict__ cfin, const int* __restrict__ cidx,
    unsigned short* __restrict__ combH, unsigned short* __restrict__ combL)
{
    int i = blockIdx.x;
    int t = threadIdx.x;
    float v = cfin[(long)cidx[i] * 256 + t];
    long b = (long)i * 512 + 256 + t;
    unsigned short h = f2bf(v);
    combH[b] = h;
    combL[b] = f2bf(v - bf2f(h));
}

// out[i] = h[i] . w + b[0]
__global__ __launch_bounds__(256) void head_final_kernel(
    const float* __restrict__ h, const float* __restrict__ w,
    const float* __restrict__ b, float* __restrict__ out, int M)
{
    int gw = blockIdx.x * 4 + (threadIdx.x >> 6);
    int lane = threadIdx.x & 63;
    if (gw >= M) return;
    const float* row = h + (long)gw * 512;
    float s = 0.f;
#pragma unroll
    for (int f = lane; f < 512; f += 64) s += row[f] * w[f];
#pragma unroll
    for (int off = 32; off; off >>= 1) s += __shfl_down(s, off);
    if (lane == 0) out[gw] = s + b[0];
}

// ------------------------------ orchestration -------------------------------
// 128x128 tiles; grid padded so XCD swizzle's 8-row-band groups stay bijective
static inline dim3 mfma_grid(int M, int N) {
    int ny = (M + 127) / 128;
    ny = (ny + 7) & ~7;
    return dim3(N / 128, ny);
}

extern "C" void kernel_launch(void* const* d_in, const int* in_sizes, int n_in,
                              void* d_out, int out_size, void* d_ws, size_t ws_size,
                              hipStream_t stream)
{
    const float* drug_x = (const float*)d_in[0];
    const float* cell_x = (const float*)d_in[1];
    const int* d_ei = (const int*)d_in[2];
    const int* c_ei = (const int*)d_in[3];
    const int* d_idx = (const int*)d_in[4];
    const int* c_idx = (const int*)d_in[5];
    const float* dW1 = (const float*)d_in[6];
    const float* db1 = (const float*)d_in[7];
    const float* cW1 = (const float*)d_in[8];
    const float* cb1 = (const float*)d_in[9];
    const float* cW2 = (const float*)d_in[10];
    const float* cb2 = (const float*)d_in[11];
    const float* gdW = (const float*)d_in[12];
    const float* gdas = (const float*)d_in[13];
    const float* gdad = (const float*)d_in[14];
    const float* gdb = (const float*)d_in[15];
    const float* g1W = (const float*)d_in[16];
    const float* g1as = (const float*)d_in[17];
    const float* g1ad = (const float*)d_in[18];
    const float* g1b = (const float*)d_in[19];
    const float* g2W = (const float*)d_in[20];
    const float* g2as = (const float*)d_in[21];
    const float* g2ad = (const float*)d_in[22];
    const float* g2b = (const float*)d_in[23];
    const float* rW1 = (const float*)d_in[24];
    const float* rb1 = (const float*)d_in[25];
    const float* rW2 = (const float*)d_in[26];
    const float* rb2 = (const float*)d_in[27];
    const float* rW3 = (const float*)d_in[28];
    const float* rb3 = (const float*)d_in[29];

    const int ND = in_sizes[0] / 128;     // 50000
    const int NC = in_sizes[1] / 735;     // 10000
    const int ED = in_sizes[2] / 2;       // 800000
    const int EC = in_sizes[3] / 2;       // 160000
    const int NB = in_sizes[4];           // 16384

    const int* d_src = d_ei;
    const int* d_dst = d_ei + ED;
    const int* c_src = c_ei;
    const int* c_dst = c_ei + EC;

    const size_t MB = 1ull << 20;
    const size_t KB = 1024;
    char* ws = (char*)d_ws;

    // ---- weight split region [0, 9MB) ----
    size_t wo = 0;
    auto walloc = [&](size_t elems) -> unsigned short* {
        unsigned short* p = (unsigned short*)(ws + wo);
        wo += ((elems * 2 + 255) & ~(size_t)255);
        return p;
    };
    unsigned short* dW1h = walloc(256 * 128);  unsigned short* dW1l = walloc(256 * 128);
    unsigned short* cW1h = walloc(1024 * 736); unsigned short* cW1l = walloc(1024 * 736);
    unsigned short* cW2h = walloc(256 * 1024); unsigned short* cW2l = walloc(256 * 1024);
    unsigned short* gdWh = walloc(256 * 256);  unsigned short* gdWl = walloc(256 * 256);
    unsigned short* g1Wh = walloc(1024 * 256); unsigned short* g1Wl = walloc(1024 * 256);
    unsigned short* g2Wh = walloc(256 * 1024); unsigned short* g2Wl = walloc(256 * 1024);
    unsigned short* rW1h = walloc(512 * 512);  unsigned short* rW1l = walloc(512 * 512);
    unsigned short* rW2h = walloc(512 * 512);  unsigned short* rW2l = walloc(512 * 512);

    // ---- small scratch [9, 16MB) ----
    float* wa_ds  = (float*)(ws + 9 * MB);
    float* wa_dd  = (float*)(ws + 9 * MB + 4 * KB);
    float* wa_c1s = (float*)(ws + 9 * MB + 8 * KB);
    float* wa_c1d = (float*)(ws + 9 * MB + 12 * KB);
    float* cas    = (float*)(ws + 9 * MB + 64 * KB);
    float* cad    = (float*)(ws + 9 * MB + 128 * KB);
    int*   coff   = (int*)(ws + 9 * MB + 192 * KB);
    int*   ccur   = (int*)(ws + 9 * MB + 256 * KB);
    int*   ccnt   = (int*)(ws + 9 * MB + 320 * KB);
    int*   cebuf  = (int*)(ws + 10 * MB);              // EC+NC ints
    float* das    = (float*)(ws + 11 * MB);
    float* dad    = (float*)(ws + 11 * MB + 256 * KB);
    int*   doff   = (int*)(ws + 11 * MB + 512 * KB);
    int*   dcur   = (int*)(ws + 11 * MB + 768 * KB);
    int*   dcnt   = (int*)(ws + 12 * MB);
    int*   debuf  = (int*)(ws + 12 * MB + 256 * KB);   // ED+ND ints -> ends ~15.7MB

    // ---- big buffers (liveness-checked) ----
    float* dbuf  = (float*)(ws + 16 * MB);                    // d0 [ND,256] [16,65)
    unsigned short* aggdh = (unsigned short*)(ws + 66 * MB);  // [NB,256] [66,74)
    unsigned short* aggdl = (unsigned short*)(ws + 75 * MB);  // [75,83)
    unsigned short* combh = (unsigned short*)(ws + 84 * MB);  // [NB,512] [84,100)
    unsigned short* combl = (unsigned short*)(ws + 101 * MB); // [101,117)
    unsigned short* c0h = (unsigned short*)(ws + 16 * MB);    // [10112,1024] [16,36)  (dbuf dead)
    unsigned short* c0l = (unsigned short*)(ws + 36 * MB);    // [36,56)
    float* c1b   = (float*)(ws + 118 * MB);                   // [NC,256] [118,128)
    unsigned short* aggch = (unsigned short*)(ws + 129 * MB); // [10112,256] [129,134.1)
    unsigned short* aggcl = (unsigned short*)(ws + 135 * MB); // [135,140.1)
    unsigned short* c2h = (unsigned short*)(ws + 16 * MB);    // [16,36)  (c0 dead)
    unsigned short* c2l = (unsigned short*)(ws + 36 * MB);    // [36,56)
    float* xc2   = (float*)(ws + 118 * MB);                   // [118,128) (c1 dead)
    float* cfin  = (float*)(ws + 141 * MB);                   // [141,151)
    unsigned short* h1h = (unsigned short*)(ws + 16 * MB);    // [NB,512] [16,32) (c2 dead)
    unsigned short* h1l = (unsigned short*)(ws + 33 * MB);    // [33,49)
    float* h2b   = (float*)(ws + 50 * MB);                    // [NB,512] fp32 [50,82)

    // ================= fused prepass: 8 splits + 4 matvecs ===================
    SJobs js;
    js.j[0] = {dW1, dW1h, dW1l, 128, 256, 128, 0};
    js.j[1] = {cW1, cW1h, cW1l, 735, 1024, 736, 32};
    js.j[2] = {cW2, cW2h, cW2l, 1024, 256, 1024, 768};
    js.j[3] = {gdW, gdWh, gdWl, 256, 256, 256, 1024};
    js.j[4] = {g1W, g1Wh, g1Wl, 256, 1024, 256, 1088};
    js.j[5] = {g2W, g2Wh, g2Wl, 1024, 256, 1024, 1344};
    js.j[6] = {rW1, rW1h, rW1l, 512, 512, 512, 1600};
    js.j[7] = {rW2, rW2h, rW2l, 512, 512, 512, 1856};
    split_transpose_multi<<<2112, 256, 0, stream>>>(js);
    matvec4<<<1024, 256, 0, stream>>>(gdW, gdas, gdad, wa_ds, wa_dd,
                                      g1W, g1as, g1ad, wa_c1s, wa_c1d);

    // ======================= drug path (batch-sparse) =======================
    // d0 = relu(drug_x @ dW1 + db1) -> fp32, full ND (any node can be a src)
    gemm2<1, 0, 0><<<mfma_grid(ND, 256), 512, 0, stream>>>(
        drug_x, nullptr, nullptr, dW1h, dW1l, db1, dbuf, nullptr, nullptr,
        ND, 128, 256, 128, 256);
    att_scalars<<<ND, 256, 0, stream>>>(dbuf, wa_ds, wa_dd, das, dad, 256);
    hipMemsetAsync(dcnt, 0, (size_t)ND * 4, stream);
    {
        int tot = ED + ND;
        hist_kernel<<<(tot + 255) / 256, 256, 0, stream>>>(d_dst, dcnt, ED, ND);
        scan_kernel<<<1, SCAN_T, 0, stream>>>(dcnt, doff, dcur, ND);
        scatter_kernel<<<(tot + 255) / 256, 256, 0, stream>>>(d_src, d_dst, dcur, debuf, ED, ND);
        // only the NB batch rows: block i aggregates dst node didx[i]
        gat_agg2<0><<<NB, 256, 0, stream>>>(doff, debuf, das, dad, dbuf, nullptr,
                                            d_idx, nullptr, aggdh, aggdl);
    }
    // comb left half = relu(aggd_batch @ gdW + gdb) as split planes (stride 512)
    gemm2<1, 1, 1><<<mfma_grid(NB, 256), 512, 0, stream>>>(
        nullptr, aggdh, aggdl, gdWh, gdWl, gdb, nullptr, combh, combl,
        NB, 256, 256, 256, 512);

    // ======================= cell path =======================
    gemm2<1, 0, 1><<<mfma_grid(NC, 1024), 512, 0, stream>>>(
        cell_x, nullptr, nullptr, cW1h, cW1l, cb1, nullptr, c0h, c0l,
        NC, 735, 1024, 736, 1024);
    gemm2<1, 1, 0><<<mfma_grid(NC, 256), 512, 0, stream>>>(
        nullptr, c0h, c0l, cW2h, cW2l, cb2, c1b, nullptr, nullptr,
        NC, 1024, 256, 1024, 256);
    att_scalars<<<NC, 256, 0, stream>>>(c1b, wa_c1s, wa_c1d, cas, cad, 256);
    hipMemsetAsync(ccnt, 0, (size_t)NC * 4, stream);
    {
        int tot = EC + NC;
        hist_kernel<<<(tot + 255) / 256, 256, 0, stream>>>(c_dst, ccnt, EC, NC);
        scan_kernel<<<1, SCAN_T, 0, stream>>>(ccnt, coff, ccur, NC);
        scatter_kernel<<<(tot + 255) / 256, 256, 0, stream>>>(c_src, c_dst, ccur, cebuf, EC, NC);
        gat_agg2<0><<<NC, 256, 0, stream>>>(coff, cebuf, cas, cad, c1b, nullptr,
                                            nullptr, nullptr, aggch, aggcl);
    }
    gemm2<1, 1, 1><<<mfma_grid(NC, 1024), 512, 0, stream>>>(
        nullptr, aggch, aggcl, g1Wh, g1Wl, g1b, nullptr, c2h, c2l,
        NC, 256, 1024, 256, 1024);
    gemm2<0, 1, 0><<<mfma_grid(NC, 256), 512, 0, stream>>>(
        nullptr, c2h, c2l, g2Wh, g2Wl, nullptr, xc2, nullptr, nullptr,
        NC, 1024, 256, 1024, 256);
    att_scalars<<<NC, 256, 0, stream>>>(xc2, g2as, g2ad, cas, cad, 256);
    gat_agg2<1><<<NC, 256, 0, stream>>>(coff, cebuf, cas, cad, xc2, g2b,
                                        nullptr, cfin, nullptr, nullptr);

    // ======================= head =======================
    gather_cell_split<<<NB, 256, 0, stream>>>(cfin, c_idx, combh, combl);
    gemm2<2, 1, 1><<<mfma_grid(NB, 512), 512, 0, stream>>>(
        nullptr, combh, combl, rW1h, rW1l, rb1, nullptr, h1h, h1l,
        NB, 512, 512, 512, 512);
    gemm2<2, 1, 0><<<mfma_grid(NB, 512), 512, 0, stream>>>(
        nullptr, h1h, h1l, rW2h, rW2l, rb2, h2b, nullptr, nullptr,
        NB, 512, 512, 512, 512);
    head_final_kernel<<<(NB + 3) / 4, 256, 0, stream>>>(h2b, rW3, rb3, (float*)d_out, NB);
}